// Round 1
// baseline (750.087 us; speedup 1.0000x reference)
//
#include <hip/hip_runtime.h>
#include <hip/hip_bf16.h>

// Problem: B=4,H=8,N=2048,DV=64. BH=32.
// P_d = stable argsort of v[:,d] (per bh). Q_d = inverse perm.
// out[r,d] = v[ P_d[ Q_{(d+1)%64}[r] ], d ]
// attn[r,:] = one_hot( P_0[ Q_1[r] ] )
// d_out = [ out (4,194,304 f32) | attn (134,217,728 f32 of 0.0/1.0) ]

#define SORT_N 2048
#define SORT_T 256
#define NBH 32
#define NDV 64

// ---------------- Kernel 1: per-column stable bitonic argsort -> P, Q -------
__global__ __launch_bounds__(SORT_T) void sort_kernel(
    const float* __restrict__ v, unsigned short* __restrict__ P,
    unsigned short* __restrict__ Q) {
  const int col = blockIdx.x;        // bh*64 + d
  const int bh  = col >> 6;
  const int d   = col & 63;
  const float* vcol = v + (size_t)bh * SORT_N * NDV + d;

  __shared__ unsigned long long key[SORT_N];   // 16 KiB
  const int tid = threadIdx.x;

  // load: key = (order-preserving bits of float << 32) | index  -> stable sort
  for (int n = tid; n < SORT_N; n += SORT_T) {
    float f = vcol[(size_t)n * NDV];
    unsigned u = __float_as_uint(f);
    u = (u & 0x80000000u) ? ~u : (u | 0x80000000u);
    key[n] = ((unsigned long long)u << 32) | (unsigned)n;
  }
  __syncthreads();

  // bitonic sort, ascending
  for (int k = 2; k <= SORT_N; k <<= 1) {
    for (int j = k >> 1; j > 0; j >>= 1) {
      for (int i = tid; i < SORT_N; i += SORT_T) {
        int ixj = i ^ j;
        if (ixj > i) {
          unsigned long long a = key[i];
          unsigned long long b = key[ixj];
          bool up = ((i & k) == 0);
          if ((a > b) == up) { key[i] = b; key[ixj] = a; }
        }
      }
      __syncthreads();
    }
  }

  unsigned short* Pcol = P + (size_t)col * SORT_N;
  unsigned short* Qcol = Q + (size_t)col * SORT_N;
  for (int r = tid; r < SORT_N; r += SORT_T) {
    int p = (int)(key[r] & 0x7FFu);  // index < 2048
    Pcol[r] = (unsigned short)p;
    Qcol[p] = (unsigned short)r;     // inverse perm by scatter
  }
}

// ---------------- Kernel 2: out[r,d] = v[P_d[Q_{d+1}[r]], d] ----------------
__global__ __launch_bounds__(256) void out_kernel(
    const float* __restrict__ v, const unsigned short* __restrict__ P,
    const unsigned short* __restrict__ Q, float* __restrict__ out) {
  size_t gid = (size_t)blockIdx.x * 256 + threadIdx.x;  // over BH*N*DV
  int d = (int)(gid & 63);
  size_t rbh = gid >> 6;
  int r  = (int)(rbh & 2047);
  int bh = (int)(rbh >> 11);
  int dn = (d + 1) & 63;
  int q = Q[((size_t)bh * NDV + dn) * SORT_N + r];
  int p = P[((size_t)bh * NDV + d)  * SORT_N + q];
  out[gid] = v[((size_t)bh * SORT_N + p) * NDV + d];
}

// ---------------- Kernel 3: attn rows, fused zero + one-hot -----------------
__global__ __launch_bounds__(256) void attn_kernel(
    const unsigned short* __restrict__ P, const unsigned short* __restrict__ Q,
    float* __restrict__ attn) {
  int row = blockIdx.x;              // bh*2048 + r
  int bh = row >> 11;
  int r  = row & 2047;
  int q   = Q[((size_t)bh * NDV + 1) * SORT_N + r];
  int idx = P[((size_t)bh * NDV + 0) * SORT_N + q];

  float4* rowp = (float4*)(attn + (size_t)row * SORT_N);
  int t = threadIdx.x;
#pragma unroll
  for (int it = 0; it < 2; ++it) {
    int f4 = t + it * 256;           // 512 float4 per row
    int base = f4 * 4;
    float4 val;
    val.x = (base + 0 == idx) ? 1.0f : 0.0f;
    val.y = (base + 1 == idx) ? 1.0f : 0.0f;
    val.z = (base + 2 == idx) ? 1.0f : 0.0f;
    val.w = (base + 3 == idx) ? 1.0f : 0.0f;
    rowp[f4] = val;
  }
}

extern "C" void kernel_launch(void* const* d_in, const int* in_sizes, int n_in,
                              void* d_out, int out_size, void* d_ws, size_t ws_size,
                              hipStream_t stream) {
  const float* v = (const float*)d_in[2];   // q,k unused by reference
  float* out  = (float*)d_out;
  float* attn = out + (size_t)NBH * SORT_N * NDV;   // +4,194,304

  unsigned short* P = (unsigned short*)d_ws;                     // 8 MiB
  unsigned short* Q = P + (size_t)NBH * NDV * SORT_N;            // 8 MiB

  // 1) 2048 column sorts
  sort_kernel<<<NBH * NDV, SORT_T, 0, stream>>>(v, P, Q);
  // 2) out gather: BH*N*DV / 256 = 16384 blocks
  out_kernel<<<(NBH * SORT_N * NDV) / 256, 256, 0, stream>>>(v, P, Q, out);
  // 3) attn: one block per row
  attn_kernel<<<NBH * SORT_N, 256, 0, stream>>>(P, Q, attn);
}

// Round 2
// 645.541 us; speedup vs baseline: 1.1619x; 1.1619x over previous
//
#include <hip/hip_runtime.h>
#include <hip/hip_bf16.h>

// B=4,H=8,N=2048,DV=64. BH=32.
// P_d = stable argsort of v[:,d] (per bh), Q_d = inverse perm, vs_d = sorted col.
// out[r,d] = vs_d[ Q_{(d+1)%64}[r] ]
// attn[r,:] = one_hot( P_0[ Q_1[r] ] )
// ws layout: Q ushort[32*64*2048] (8MB) | vs float[32*64*2048] (16MB) | P0 ushort[32*2048]

#define SORT_N 2048
#define SORT_T 256
#define NBH 32
#define NDV 64
#define SLOT(i) ((i) + ((i) >> 3))   // +1 u64 pad per 8 elems: breaks 64B-stride bank aliasing

__device__ __forceinline__ void ce(unsigned long long& a, unsigned long long& b, bool up) {
  if ((a > b) == up) { unsigned long long t = a; a = b; b = t; }
}

// ---------------- Kernel 1: hybrid bitonic stable argsort -> Q, vs, P0 ------
__global__ __launch_bounds__(SORT_T) void sort_kernel(
    const float* __restrict__ v, unsigned short* __restrict__ Q,
    float* __restrict__ vs, unsigned short* __restrict__ P0) {
  const int col = blockIdx.x;        // bh*64 + d
  const int bh  = col >> 6;
  const int d   = col & 63;
  const float* vcol = v + (size_t)bh * SORT_N * NDV + d;

  __shared__ unsigned long long key[SORT_N + SORT_N / 8];  // 18 KiB padded
  const int t = threadIdx.x;
  const int base = t * 8;            // thread owns elements [base, base+8)

  unsigned long long r[8];
#pragma unroll
  for (int e = 0; e < 8; ++e) {
    float f = vcol[(size_t)(base + e) * NDV];
    unsigned u = __float_as_uint(f);
    u = (u & 0x80000000u) ? ~u : (u | 0x80000000u);   // order-preserving bias
    r[e] = ((unsigned long long)u << 32) | (unsigned)(base + e);  // stable
  }

  // phases k=2,4,8 entirely in registers (no barriers)
#pragma unroll
  for (int e = 0; e < 8; e += 2) ce(r[e], r[e + 1], ((base + e) & 2) == 0);
#pragma unroll
  for (int e0 = 0; e0 < 8; e0 += 4) {
    bool up4 = ((base + e0) & 4) == 0;
    ce(r[e0], r[e0 + 2], up4); ce(r[e0 + 1], r[e0 + 3], up4);
    ce(r[e0], r[e0 + 1], up4); ce(r[e0 + 2], r[e0 + 3], up4);
  }
  {
    bool up8 = (base & 8) == 0;
    ce(r[0], r[4], up8); ce(r[1], r[5], up8); ce(r[2], r[6], up8); ce(r[3], r[7], up8);
    ce(r[0], r[2], up8); ce(r[1], r[3], up8); ce(r[4], r[6], up8); ce(r[5], r[7], up8);
    ce(r[0], r[1], up8); ce(r[2], r[3], up8); ce(r[4], r[5], up8); ce(r[6], r[7], up8);
  }
#pragma unroll
  for (int e = 0; e < 8; ++e) key[SLOT(base + e)] = r[e];
  __syncthreads();

  for (int k = 16; k <= SORT_N; k <<= 1) {
    // LDS passes j = k/2 .. 8 : dense pair enumeration, 4 pairs/thread
    for (int j = k >> 1; j >= 8; j >>= 1) {
#pragma unroll
      for (int s = 0; s < 4; ++s) {
        int p = t + s * SORT_T;           // pair index 0..1023
        int low = p & (j - 1);
        int i = ((p ^ low) << 1) | low;   // lower element of pair
        bool up = (i & k) == 0;
        unsigned long long a = key[SLOT(i)];
        unsigned long long b = key[SLOT(i + j)];
        if ((a > b) == up) { key[SLOT(i)] = b; key[SLOT(i + j)] = a; }
      }
      __syncthreads();
    }
    // j = 4,2,1 in registers (direction uniform per chunk since k >= 16)
#pragma unroll
    for (int e = 0; e < 8; ++e) r[e] = key[SLOT(base + e)];
    bool up = (base & k) == 0;
    ce(r[0], r[4], up); ce(r[1], r[5], up); ce(r[2], r[6], up); ce(r[3], r[7], up);
    ce(r[0], r[2], up); ce(r[1], r[3], up); ce(r[4], r[6], up); ce(r[5], r[7], up);
    ce(r[0], r[1], up); ce(r[2], r[3], up); ce(r[4], r[5], up); ce(r[6], r[7], up);
#pragma unroll
    for (int e = 0; e < 8; ++e) key[SLOT(base + e)] = r[e];
    __syncthreads();
  }

  unsigned short* Qcol = Q + (size_t)col * SORT_N;
  float* vscol = vs + (size_t)col * SORT_N;
#pragma unroll
  for (int s = 0; s < 8; ++s) {
    int rr = t + s * SORT_T;
    unsigned long long kk = key[SLOT(rr)];
    int p = (int)(kk & 2047u);
    unsigned u = (unsigned)(kk >> 32);
    float f = (u & 0x80000000u) ? __uint_as_float(u & 0x7fffffffu)
                                : __uint_as_float(~u);
    Qcol[p] = (unsigned short)rr;     // inverse perm by scatter
    vscol[rr] = f;                    // sorted values, contiguous
    if (d == 0) P0[(size_t)bh * SORT_N + rr] = (unsigned short)p;
  }
}

// ---------------- Kernel 2: out[r,d] = vs_d[Q_{d+1}[r]] ---------------------
__global__ __launch_bounds__(256) void out_kernel(
    const unsigned short* __restrict__ Q, const float* __restrict__ vs,
    float* __restrict__ out) {
  int gid = blockIdx.x * 256 + threadIdx.x;   // over BH*N*DV, d fastest
  int d = gid & 63;
  int rbh = gid >> 6;
  int r  = rbh & 2047;
  int bh = rbh >> 11;
  int dn = (d + 1) & 63;
  int q = Q[(((bh << 6) + dn) << 11) + r];    // near-L1-resident gather
  out[gid] = vs[(((bh << 6) + d) << 11) + q]; // single remaining scattered gather
}

// ---------------- Kernel 3: attn rows, fused zero + one-hot -----------------
__global__ __launch_bounds__(256) void attn_kernel(
    const unsigned short* __restrict__ P0, const unsigned short* __restrict__ Q,
    float* __restrict__ attn) {
  int row = blockIdx.x;              // bh*2048 + r
  int bh = row >> 11;
  int r  = row & 2047;
  int q   = Q[(((bh << 6) + 1) << 11) + r];   // Q_1[r]
  int idx = P0[(bh << 11) + q];               // P_0[Q_1[r]]
  float4* rowp = (float4*)(attn + (size_t)row * SORT_N);
  int t = threadIdx.x;
#pragma unroll
  for (int it = 0; it < 2; ++it) {
    int f4 = t + it * 256;
    int basei = f4 * 4;
    float4 val;
    val.x = (basei + 0 == idx) ? 1.0f : 0.0f;
    val.y = (basei + 1 == idx) ? 1.0f : 0.0f;
    val.z = (basei + 2 == idx) ? 1.0f : 0.0f;
    val.w = (basei + 3 == idx) ? 1.0f : 0.0f;
    rowp[f4] = val;
  }
}

extern "C" void kernel_launch(void* const* d_in, const int* in_sizes, int n_in,
                              void* d_out, int out_size, void* d_ws, size_t ws_size,
                              hipStream_t stream) {
  const float* v = (const float*)d_in[2];     // q,k unused by reference
  float* out  = (float*)d_out;
  float* attn = out + (size_t)NBH * SORT_N * NDV;

  unsigned short* Q  = (unsigned short*)d_ws;                             // 8 MiB
  float* vs          = (float*)((char*)d_ws + (size_t)8 * 1024 * 1024);   // 16 MiB
  unsigned short* P0 = (unsigned short*)((char*)d_ws + (size_t)24 * 1024 * 1024);

  sort_kernel<<<NBH * NDV, SORT_T, 0, stream>>>(v, Q, vs, P0);
  out_kernel<<<(NBH * SORT_N * NDV) / 256, 256, 0, stream>>>(Q, vs, out);
  attn_kernel<<<NBH * SORT_N, 256, 0, stream>>>(P0, Q, attn);
}

// Round 6
// 626.052 us; speedup vs baseline: 1.1981x; 1.0311x over previous
//
#include <hip/hip_runtime.h>
#include <hip/hip_bf16.h>

// B=4,H=8,N=2048,DV=64. BH=32.
// P_d = stable argsort of v[:,d] (per bh), Q_d = inverse perm, vs_d = sorted col.
// out[r,d] = vs_d[ Q_{(d+1)%64}[r] ]
// attn[r,:] = one_hot( P_0[ Q_1[r] ] )
// ws: Q ushort[32*64*2048] (8MB) | vs float[32*64*2048] (16MB) | P0 ushort[32*2048]
// outT scratch (16MB) lives at the start of the attn region of d_out; it is
// fully consumed by out_transpose before attn_kernel overwrites the region.

#define SORT_N 2048
#define SORT_T 256
#define NBH 32
#define NDV 64
#define SLOT(i) ((i) + ((i) >> 3))   // +1 u64 pad per 8 elems: breaks 64B-stride bank aliasing

__device__ __forceinline__ void ce(unsigned long long& a, unsigned long long& b, bool up) {
  if ((a > b) == up) { unsigned long long t = a; a = b; b = t; }
}

// ---------------- Kernel 1: hybrid bitonic stable argsort -> Q, vs, P0 ------
// (byte-identical to the R2 version that compiled and passed)
__global__ __launch_bounds__(SORT_T) void sort_kernel(
    const float* __restrict__ v, unsigned short* __restrict__ Q,
    float* __restrict__ vs, unsigned short* __restrict__ P0) {
  const int col = blockIdx.x;        // bh*64 + d
  const int bh  = col >> 6;
  const int d   = col & 63;
  const float* vcol = v + (size_t)bh * SORT_N * NDV + d;

  __shared__ unsigned long long key[SORT_N + SORT_N / 8];  // 18 KiB padded
  const int t = threadIdx.x;
  const int base = t * 8;            // thread owns elements [base, base+8)

  unsigned long long r[8];
#pragma unroll
  for (int e = 0; e < 8; ++e) {
    float f = vcol[(size_t)(base + e) * NDV];
    unsigned u = __float_as_uint(f);
    u = (u & 0x80000000u) ? ~u : (u | 0x80000000u);   // order-preserving bias
    r[e] = ((unsigned long long)u << 32) | (unsigned)(base + e);  // stable
  }

  // phases k=2,4,8 entirely in registers (no barriers)
#pragma unroll
  for (int e = 0; e < 8; e += 2) ce(r[e], r[e + 1], ((base + e) & 2) == 0);
#pragma unroll
  for (int e0 = 0; e0 < 8; e0 += 4) {
    bool up4 = ((base + e0) & 4) == 0;
    ce(r[e0], r[e0 + 2], up4); ce(r[e0 + 1], r[e0 + 3], up4);
    ce(r[e0], r[e0 + 1], up4); ce(r[e0 + 2], r[e0 + 3], up4);
  }
  {
    bool up8 = (base & 8) == 0;
    ce(r[0], r[4], up8); ce(r[1], r[5], up8); ce(r[2], r[6], up8); ce(r[3], r[7], up8);
    ce(r[0], r[2], up8); ce(r[1], r[3], up8); ce(r[4], r[6], up8); ce(r[5], r[7], up8);
    ce(r[0], r[1], up8); ce(r[2], r[3], up8); ce(r[4], r[5], up8); ce(r[6], r[7], up8);
  }
#pragma unroll
  for (int e = 0; e < 8; ++e) key[SLOT(base + e)] = r[e];
  __syncthreads();

  for (int k = 16; k <= SORT_N; k <<= 1) {
    // LDS passes j = k/2 .. 8 : dense pair enumeration, 4 pairs/thread
    for (int j = k >> 1; j >= 8; j >>= 1) {
#pragma unroll
      for (int s = 0; s < 4; ++s) {
        int p = t + s * SORT_T;           // pair index 0..1023
        int low = p & (j - 1);
        int i = ((p ^ low) << 1) | low;   // lower element of pair
        bool up = (i & k) == 0;
        unsigned long long a = key[SLOT(i)];
        unsigned long long b = key[SLOT(i + j)];
        if ((a > b) == up) { key[SLOT(i)] = b; key[SLOT(i + j)] = a; }
      }
      __syncthreads();
    }
    // j = 4,2,1 in registers (direction uniform per chunk since k >= 16)
#pragma unroll
    for (int e = 0; e < 8; ++e) r[e] = key[SLOT(base + e)];
    bool up = (base & k) == 0;
    ce(r[0], r[4], up); ce(r[1], r[5], up); ce(r[2], r[6], up); ce(r[3], r[7], up);
    ce(r[0], r[2], up); ce(r[1], r[3], up); ce(r[4], r[6], up); ce(r[5], r[7], up);
    ce(r[0], r[1], up); ce(r[2], r[3], up); ce(r[4], r[5], up); ce(r[6], r[7], up);
#pragma unroll
    for (int e = 0; e < 8; ++e) key[SLOT(base + e)] = r[e];
    __syncthreads();
  }

  unsigned short* Qcol = Q + (size_t)col * SORT_N;
  float* vscol = vs + (size_t)col * SORT_N;
#pragma unroll
  for (int s = 0; s < 8; ++s) {
    int rr = t + s * SORT_T;
    unsigned long long kk = key[SLOT(rr)];
    int p = (int)(kk & 2047u);
    unsigned u = (unsigned)(kk >> 32);
    float f = (u & 0x80000000u) ? __uint_as_float(u & 0x7fffffffu)
                                : __uint_as_float(~u);
    Qcol[p] = (unsigned short)rr;     // inverse perm by scatter
    vscol[rr] = f;                    // sorted values, contiguous
    if (d == 0) P0[(size_t)bh * SORT_N + rr] = (unsigned short)p;
  }
}

// ------- Kernel 2a: outT[(bh,d)][r] = vs_d[Q_{d+1}[r]]  (all coalesced) -----
// One block per (bh,d): stage vs-column (8KB) in LDS, gather from LDS.
__global__ __launch_bounds__(256) void out_colT_kernel(
    const unsigned short* __restrict__ Q, const float* __restrict__ vs,
    float* __restrict__ outT) {
  const int b  = blockIdx.x;         // bh*64 + d
  const int bh = b >> 6;
  const int d  = b & 63;
  const int dn = (d + 1) & 63;
  const int t  = threadIdx.x;

  __shared__ float col[SORT_N];      // 8 KiB
  const float* vcol = vs + ((size_t)b << 11);
  for (int r = t; r < SORT_N; r += 256) col[r] = vcol[r];   // coalesced
  __syncthreads();

  const unsigned short* Qcol = Q + ((size_t)((bh << 6) + dn) << 11);
  float* ocol = outT + ((size_t)b << 11);
  for (int r = t; r < SORT_N; r += 256) {
    int q = Qcol[r];                 // coalesced ushort read
    ocol[r] = col[q];                // LDS gather + coalesced write
  }
}

// ------- Kernel 2b: out[r][d] = outT[d][r]  (64x64 LDS tile transpose) ------
__global__ __launch_bounds__(256) void out_transpose_kernel(
    const float* __restrict__ outT, float* __restrict__ out) {
  __shared__ float tile[64][65];     // +1 pad breaks bank conflicts
  const int blk = blockIdx.x;        // bh*32 + rtile
  const int bh = blk >> 5;
  const int r0 = (blk & 31) << 6;    // 64-row tile
  const int tx = threadIdx.x & 63;
  const int ty = threadIdx.x >> 6;   // 0..3

  for (int i = ty; i < 64; i += 4)   // read outT[d=i][r0+tx] coalesced
    tile[i][tx] = outT[(((size_t)(bh << 6) + i) << 11) + r0 + tx];
  __syncthreads();
  for (int i = ty; i < 64; i += 4)   // write out[r0+i][d=tx] coalesced
    out[(((size_t)(bh << 11) + r0 + i) << 6) + tx] = tile[tx][i];
}

// ---------------- Kernel 3: attn rows, fused zero + one-hot -----------------
__global__ __launch_bounds__(256) void attn_kernel(
    const unsigned short* __restrict__ P0, const unsigned short* __restrict__ Q,
    float* __restrict__ attn) {
  int row = blockIdx.x;              // bh*2048 + r
  int bh = row >> 11;
  int r  = row & 2047;
  int q   = Q[(((bh << 6) + 1) << 11) + r];   // Q_1[r]
  int idx = P0[(bh << 11) + q];               // P_0[Q_1[r]]
  float4* rowp = (float4*)(attn + (size_t)row * SORT_N);
  int t = threadIdx.x;
#pragma unroll
  for (int it = 0; it < 2; ++it) {
    int f4 = t + it * 256;
    int basei = f4 * 4;
    float4 val;
    val.x = (basei + 0 == idx) ? 1.0f : 0.0f;
    val.y = (basei + 1 == idx) ? 1.0f : 0.0f;
    val.z = (basei + 2 == idx) ? 1.0f : 0.0f;
    val.w = (basei + 3 == idx) ? 1.0f : 0.0f;
    rowp[f4] = val;
  }
}

extern "C" void kernel_launch(void* const* d_in, const int* in_sizes, int n_in,
                              void* d_out, int out_size, void* d_ws, size_t ws_size,
                              hipStream_t stream) {
  const float* v = (const float*)d_in[2];     // q,k unused by reference
  float* out  = (float*)d_out;
  float* attn = out + (size_t)NBH * SORT_N * NDV;
  float* outT = attn;                          // 16MB scratch, consumed before attn write

  unsigned short* Q  = (unsigned short*)d_ws;                             // 8 MiB
  float* vs          = (float*)((char*)d_ws + (size_t)8 * 1024 * 1024);   // 16 MiB
  unsigned short* P0 = (unsigned short*)((char*)d_ws + (size_t)24 * 1024 * 1024);

  sort_kernel<<<NBH * NDV, SORT_T, 0, stream>>>(v, Q, vs, P0);
  out_colT_kernel<<<NBH * NDV, 256, 0, stream>>>(Q, vs, outT);
  out_transpose_kernel<<<NBH * 32, 256, 0, stream>>>(outT, out);
  attn_kernel<<<NBH * SORT_N, 256, 0, stream>>>(P0, Q, attn);
}